// Round 8
// baseline (111.745 us; speedup 1.0000x reference)
//
#include <hip/hip_runtime.h>
#include <math.h>

#define N_PROP 1000
#define N_CLS  81
#define N_FG   80
#define SCORE_THRESH 0.05f
#define NMS_THRESH   0.5f
#define DET_PER_IMG  100
#define BBOX_CLIP    4.135166556742356f   // ln(1000/16)

// d_out layout (560000 floats):
//   [0, 400000)        out5: (80*1000, 5)
//   [400000, 480000)   labels as float
//   [480000, 560000)   final mask as 0.0/1.0
#define LBL_OFF    400000
#define FIN_OFF    480000

// ws layout (bytes):
//   [0, 320)            int   svCnt[80]      (plain stores, rewritten each run)
//   [1024, 328704)      float svScore[80*1024]
//   [328704, 656384)    int   svRow[80*1024]
#define SV_STRIDE 1024

#define CHUNK 125   // proposals staged per softmax chunk (8 chunks x 125 = 1000)

__device__ __forceinline__ void decode_box(const float* __restrict__ props,
                                           const float* __restrict__ reg,
                                           int j, int cls, float W1, float H1,
                                           float& bx1, float& by1, float& bx2,
                                           float& by2, float& area) {
    float4 pr = *(const float4*)(props + (size_t)j * 4);
    float w  = pr.z - pr.x + 1.0f;
    float h  = pr.w - pr.y + 1.0f;
    float cx = pr.x + 0.5f * w;
    float cy = pr.y + 0.5f * h;
    float4 rr = *(const float4*)(reg + ((size_t)j * N_CLS + cls) * 4);
    float dx = rr.x / 10.0f;
    float dy = rr.y / 10.0f;
    float dw = fminf(rr.z / 5.0f, BBOX_CLIP);
    float dh = fminf(rr.w / 5.0f, BBOX_CLIP);
    float pcx = dx * w + cx;
    float pcy = dy * h + cy;
    float pw = expf(dw) * w;
    float ph = expf(dh) * h;
    bx1 = fminf(fmaxf(pcx - 0.5f * pw, 0.0f), W1);
    by1 = fminf(fmaxf(pcy - 0.5f * ph, 0.0f), H1);
    bx2 = fminf(fmaxf(pcx + 0.5f * pw - 1.0f, 0.0f), W1);
    by2 = fminf(fmaxf(pcy + 0.5f * ph - 1.0f, 0.0f), H1);
    area = (bx2 - bx1 + 1.0f) * (by2 - by1 + 1.0f);
}

// ---------- K_A: one block per class, fully self-contained ----------
__global__ __launch_bounds__(256)
void nms_all_kernel(const float* __restrict__ logits,
                    const float* __restrict__ reg,
                    const float* __restrict__ props,
                    const int* __restrict__ ihp,
                    const int* __restrict__ iwp,
                    float* __restrict__ out,
                    int* __restrict__ svCnt,
                    float* __restrict__ svScore,
                    int* __restrict__ svRow) {
    const int c = blockIdx.x;     // 0..79
    const int t = threadIdx.x;    // 0..255
    const int lane = t & 63;
    const int cls = c + 1;

    __shared__ float sLog[CHUNK * N_CLS];   // 40.5 KB staging
    __shared__ float sSc[N_PROP];
    __shared__ int   sIdx[N_PROP];
    __shared__ float sx1[512], sy1[512], sx2[512], sy2[512], sar[512], sSc2[512];
    __shared__ int   sJdx[512];
    __shared__ unsigned long long smask[512][8];   // 32 KB; aliased by fallback
    __shared__ unsigned long long skeepW[8];
    __shared__ int   sWp[9];
    __shared__ int   shV;

    // ---- phase 0: zero own output slice ----
    {
        float4 z = make_float4(0.f, 0.f, 0.f, 0.f);
        float4* o5 = (float4*)(out + (size_t)c * N_PROP * 5);
        for (int i = t; i < 1250; i += 256) o5[i] = z;
        float4* lb = (float4*)(out + LBL_OFF + (size_t)c * N_PROP);
        float4* fm = (float4*)(out + FIN_OFF + (size_t)c * N_PROP);
        for (int i = t; i < 250; i += 256) { lb[i] = z; fm[i] = z; }
    }

    // ---- phase 1: class-c scores, LDS-staged coalesced softmax ----
    for (int ch = 0; ch < 8; ++ch) {
        const float* src = logits + (size_t)ch * CHUNK * N_CLS;
        __syncthreads();                       // protect sLog reuse
        for (int i = t; i < CHUNK * N_CLS; i += 256) sLog[i] = src[i];
        __syncthreads();
        if (t < CHUNK) {
            const float* lr = sLog + t * N_CLS;
            float m = lr[0];
            for (int k = 1; k < N_CLS; ++k) m = fmaxf(m, lr[k]);
            float s = 0.0f;
            for (int k = 0; k < N_CLS; ++k) s += expf(lr[k] - m);
            sSc[ch * CHUNK + t] = expf(lr[cls] - m) / s;   // same chain as R5 (absmax 0.0)
        }
    }
    __syncthreads();

    // ---- phase 2: wave-0 ballot compaction (in place, lockstep-safe) ----
    if (t < 64) {
        const unsigned long long lm = (1ull << lane) - 1ull;
        int V = 0;
        #pragma unroll
        for (int it = 0; it < 16; ++it) {
            int j = it * 64 + lane;
            float sc = (j < N_PROP) ? sSc[j] : -1.0f;
            bool val = (j < N_PROP) && (sc > SCORE_THRESH);
            unsigned long long mask = __ballot(val);
            if (val) { int p = V + __popcll(mask & lm); sSc[p] = sc; sIdx[p] = j; }
            V += __popcll(mask);
        }
        if (lane == 0) shV = V;
    }
    __syncthreads();
    const int V = shV;

    const float W1 = (float)iwp[0] - 1.0f;
    const float H1 = (float)ihp[0] - 1.0f;

    if (V <= 512) {
        // ---- phase 3: fused stable-rank + decode into sorted slots ----
        for (int v = t; v < V; v += 256) {
            float s = sSc[v];
            int id = sIdx[v];
            int r = 0;
            for (int u = 0; u < V; ++u) {
                float su = sSc[u];
                r += (su > s) || (su == s && sIdx[u] < id);
            }
            float bx1, by1, bx2, by2, ar;
            decode_box(props, reg, id, cls, W1, H1, bx1, by1, bx2, by2, ar);
            sx1[r] = bx1; sy1[r] = by1; sx2[r] = bx2; sy2[r] = by2;
            sar[r] = ar; sSc2[r] = s; sJdx[r] = id;
        }
        __syncthreads();

        // ---- phase 4: parallel IoU bitmask build ----
        const int nW = (V + 63) >> 6;
        for (int r = t; r < V; r += 256) {
            const float X1 = sx1[r], Y1 = sy1[r], X2 = sx2[r], Y2 = sy2[r], A = sar[r];
            for (int w = 0; w < nW; ++w) {
                unsigned long long bits = 0ull;
                int v0 = w << 6;
                int vs = (r + 1 > v0) ? r + 1 : v0;
                int ve = (V < v0 + 64) ? V : v0 + 64;
                for (int v = vs; v < ve; ++v) {
                    float iw = fmaxf(fminf(X2, sx2[v]) - fmaxf(X1, sx1[v]) + 1.0f, 0.0f);
                    float ih = fmaxf(fminf(Y2, sy2[v]) - fmaxf(Y1, sy1[v]) + 1.0f, 0.0f);
                    float inter = iw * ih;
                    float iou = inter / (A + sar[v] - inter);
                    if (iou > NMS_THRESH) bits |= 1ull << (v - v0);   // NaN-safe
                }
                smask[r][w] = bits;
            }
        }
        __syncthreads();

        // ---- phase 5: single-thread greedy bit scan (== sorted sequential NMS) ----
        if (t == 0) {
            for (int w = 0; w < 8; ++w) {
                int rem = V - (w << 6);
                skeepW[w] = (rem >= 64) ? ~0ull : (rem <= 0 ? 0ull : ((1ull << rem) - 1ull));
            }
            for (int r = 0; r < V; ++r) {
                if ((skeepW[r >> 6] >> (r & 63)) & 1ull) {
                    for (int w = r >> 6; w < nW; ++w) skeepW[w] &= ~smask[r][w];
                }
            }
            int a = 0;
            for (int w = 0; w < 8; ++w) { sWp[w] = a; a += __popcll(skeepW[w]); }
            sWp[8] = a;
        }
        __syncthreads();

        // ---- phase 6: atomic-free survivor writes ----
        for (int v = t; v < V; v += 256) {
            unsigned long long wrd = skeepW[v >> 6];
            if ((wrd >> (v & 63)) & 1ull) {
                int pos = sWp[v >> 6] + __popcll(wrd & ((1ull << (v & 63)) - 1ull));
                int row = c * N_PROP + sJdx[v];
                size_t o = (size_t)row * 5;
                out[o + 0] = sx1[v]; out[o + 1] = sy1[v];
                out[o + 2] = sx2[v]; out[o + 3] = sy2[v];
                out[o + 4] = sSc2[v];
                out[LBL_OFF + row] = (float)cls;
                out[FIN_OFF + row] = 1.0f;
                svScore[c * SV_STRIDE + pos] = sSc2[v];
                svRow[c * SV_STRIDE + pos] = row;
            }
        }
        if (t == 0) svCnt[c] = sWp[8];
    } else {
        // ---- cold fallback (V > 512): arrays carved from smask region ----
        float* fx1 = (float*)smask;
        float* fy1 = fx1 + 1000;
        float* fx2 = fx1 + 2000;
        float* fy2 = fx1 + 3000;
        float* fa  = fx1 + 4000;
        float* fs  = fx1 + 5000;
        int*   fj  = (int*)(fx1 + 6000);
        int*   fk  = (int*)(fx1 + 7000);
        for (int v = t; v < V; v += 256) {
            float s = sSc[v];
            int id = sIdx[v];
            int r = 0;
            for (int u = 0; u < V; ++u) {
                float su = sSc[u];
                r += (su > s) || (su == s && sIdx[u] < id);
            }
            float bx1, by1, bx2, by2, ar;
            decode_box(props, reg, id, cls, W1, H1, bx1, by1, bx2, by2, ar);
            fx1[r] = bx1; fy1[r] = by1; fx2[r] = bx2; fy2[r] = by2;
            fa[r] = ar; fs[r] = s; fj[r] = id; fk[r] = 1;
        }
        __syncthreads();
        for (int r = 0; r < V; ++r) {
            if (fk[r]) {
                const float X1 = fx1[r], Y1 = fy1[r], X2 = fx2[r], Y2 = fy2[r], A = fa[r];
                for (int v = r + 1 + t; v < V; v += 256) {
                    if (fk[v]) {
                        float iw = fmaxf(fminf(X2, fx2[v]) - fmaxf(X1, fx1[v]) + 1.0f, 0.0f);
                        float ih = fmaxf(fminf(Y2, fy2[v]) - fmaxf(Y1, fy1[v]) + 1.0f, 0.0f);
                        float inter = iw * ih;
                        float iou = inter / (A + fa[v] - inter);
                        if (iou > NMS_THRESH) fk[v] = 0;
                    }
                }
            }
            __syncthreads();
        }
        // prefix positions (reuse sIdx), then parallel writes
        if (t == 0) {
            int acc = 0;
            for (int v = 0; v < V; ++v) { sIdx[v] = acc; acc += fk[v]; }
            shV = acc;   // reuse as kept-count
        }
        __syncthreads();
        for (int v = t; v < V; v += 256) {
            if (fk[v]) {
                int pos = sIdx[v];
                int row = c * N_PROP + fj[v];
                size_t o = (size_t)row * 5;
                out[o + 0] = fx1[v]; out[o + 1] = fy1[v];
                out[o + 2] = fx2[v]; out[o + 3] = fy2[v];
                out[o + 4] = fs[v];
                out[LBL_OFF + row] = (float)cls;
                out[FIN_OFF + row] = 1.0f;
                svScore[c * SV_STRIDE + pos] = fs[v];
                svRow[c * SV_STRIDE + pos] = row;
            }
        }
        if (t == 0) svCnt[c] = shV;
    }
}

// ---------- K_B: threshold + fixup ----------
__global__ __launch_bounds__(256)
void finalize_kernel(float* __restrict__ out,
                     const int* __restrict__ svCnt,
                     const float* __restrict__ svScore,
                     const int* __restrict__ svRow) {
    __shared__ int   cnt[N_FG];
    __shared__ int   off[N_FG + 1];
    __shared__ float lsc[8192];
    __shared__ int   red4[4];
    const int t = threadIdx.x;
    const int lane = t & 63;
    const int wave = t >> 6;

    if (t < N_FG) cnt[t] = svCnt[t];
    __syncthreads();
    if (t == 0) {
        int a = 0;
        for (int c = 0; c < N_FG; ++c) { off[c] = a; a += cnt[c]; }
        off[N_FG] = a;
    }
    __syncthreads();
    const int n = off[N_FG];
    if (n <= DET_PER_IMG) return;   // th=0 -> all survivors pass; uniform exit

    const bool useL = (n <= 8192);
    if (useL) {
        for (int g = t; g < n; g += 256) {
            int lo = 0, hi = N_FG;   // class with off[lo] <= g < off[lo+1]
            while (hi - lo > 1) { int mid = (lo + hi) >> 1; if (off[mid] <= g) lo = mid; else hi = mid; }
            lsc[g] = svScore[lo * SV_STRIDE + (g - off[lo])];
        }
        __syncthreads();
    }

    unsigned blo = 0x3D4CCCCCu, bhi = 0x40000000u;   // scores in (0.05, 1.0]
    while (bhi - blo > 1u) {
        unsigned mid = blo + ((bhi - blo) >> 1);
        float mv = __uint_as_float(mid);
        int cgt = 0;
        if (useL) {
            for (int g = t; g < n; g += 256) cgt += (lsc[g] >= mv) ? 1 : 0;
        } else {
            for (int g = t; g < n; g += 256) {
                int lo = 0, hi = N_FG;
                while (hi - lo > 1) { int mid2 = (lo + hi) >> 1; if (off[mid2] <= g) lo = mid2; else hi = mid2; }
                cgt += (svScore[lo * SV_STRIDE + (g - off[lo])] >= mv) ? 1 : 0;
            }
        }
        for (int o = 32; o; o >>= 1) cgt += __shfl_down(cgt, o);
        if (lane == 0) red4[wave] = cgt;
        __syncthreads();
        int total = red4[0] + red4[1] + red4[2] + red4[3];
        __syncthreads();
        if (total >= DET_PER_IMG + 1) blo = mid; else bhi = mid;
    }
    const float th = __uint_as_float(blo);

    // fixup: zero rows whose score fails the image threshold
    for (int g = t; g < n; g += 256) {
        int lo = 0, hi = N_FG;
        while (hi - lo > 1) { int mid = (lo + hi) >> 1; if (off[mid] <= g) lo = mid; else hi = mid; }
        float sc = useL ? lsc[g] : svScore[lo * SV_STRIDE + (g - off[lo])];
        if (sc < th) {
            int row = svRow[lo * SV_STRIDE + (g - off[lo])];
            size_t o = (size_t)row * 5;
            out[o + 0] = 0.0f; out[o + 1] = 0.0f; out[o + 2] = 0.0f;
            out[o + 3] = 0.0f; out[o + 4] = 0.0f;
            out[LBL_OFF + row] = 0.0f;
            out[FIN_OFF + row] = 0.0f;
        }
    }
}

extern "C" void kernel_launch(void* const* d_in, const int* in_sizes, int n_in,
                              void* d_out, int out_size, void* d_ws, size_t ws_size,
                              hipStream_t stream) {
    const float* logits = (const float*)d_in[0];
    const float* reg    = (const float*)d_in[1];
    const float* props  = (const float*)d_in[2];
    const int*   ihp    = (const int*)d_in[3];
    const int*   iwp    = (const int*)d_in[4];
    float* out = (float*)d_out;

    char* ws = (char*)d_ws;
    int*   svCnt   = (int*)(ws + 0);
    float* svScore = (float*)(ws + 1024);
    int*   svRow   = (int*)(ws + 328704);

    nms_all_kernel<<<N_FG, 256, 0, stream>>>(logits, reg, props, ihp, iwp,
                                             out, svCnt, svScore, svRow);
    finalize_kernel<<<1, 256, 0, stream>>>(out, svCnt, svScore, svRow);
}

// Round 9
// 110.127 us; speedup vs baseline: 1.0147x; 1.0147x over previous
//
#include <hip/hip_runtime.h>
#include <math.h>

#define N_PROP 1000
#define N_CLS  81
#define N_FG   80
#define SCORE_THRESH 0.05f
#define NMS_THRESH   0.5f
#define DET_PER_IMG  100
#define BBOX_CLIP    4.135166556742356f   // ln(1000/16)

// d_out layout (560000 floats):
//   [0, 400000)        out5: (80*1000, 5)
//   [400000, 480000)   labels as float
//   [480000, 560000)   final mask as 0.0/1.0
#define LBL_OFF    400000
#define FIN_OFF    480000

// ws layout (bytes):
//   [0,4)               int   survivor count
//   [4,8)               int   done counter (last-block flag)
//   [64, 320064)        float probT[80][1000]
//   [320064, 640064)    float compact survivor scores
//   [640064, 960064)    int   survivor row ids (c*1000+j)

// ---------------- K1: zero output + softmax -> probT (R4-proven) ----------
__global__ __launch_bounds__(256)
void softmax_zero_kernel(const float* __restrict__ logits,
                         float* __restrict__ out,
                         int* __restrict__ count,
                         int* __restrict__ done,
                         float* __restrict__ probT) {
    const int b = blockIdx.x;
    const int t = threadIdx.x;
    const int lane = t & 63;
    const int wave = t >> 6;
    if (b == 0 && t == 0) { *count = 0; *done = 0; }

    float4 z = make_float4(0.f, 0.f, 0.f, 0.f);
    float4* o4 = (float4*)out;
    for (int i = b * 256 + t; i < 140000; i += 250 * 256) o4[i] = z;

    const int n = b * 4 + wave;           // 250 blocks * 4 waves = 1000
    if (n < N_PROP) {
        const float* lrow = logits + (size_t)n * N_CLS;
        float v0 = lrow[lane];
        float v1 = (lane + 64 < N_CLS) ? lrow[lane + 64] : -INFINITY;
        float m = fmaxf(v0, v1);
        for (int off = 32; off; off >>= 1) m = fmaxf(m, __shfl_down(m, off));
        m = __shfl(m, 0);
        float e0 = expf(v0 - m);
        float e1 = (lane + 64 < N_CLS) ? expf(v1 - m) : 0.0f;
        float s = e0 + e1;
        for (int off = 32; off; off >>= 1) s += __shfl_down(s, off);
        s = __shfl(s, 0);
        if (lane >= 1)          probT[(size_t)(lane - 1) * N_PROP + n] = e0 / s;
        if (lane + 64 < N_CLS)  probT[(size_t)(lane + 63) * N_PROP + n] = e1 / s;
    }
}

__device__ __forceinline__ void decode_box(const float* __restrict__ props,
                                           const float* __restrict__ reg,
                                           int j, int cls, float W1, float H1,
                                           float& bx1, float& by1, float& bx2,
                                           float& by2, float& area) {
    float4 pr = *(const float4*)(props + (size_t)j * 4);
    float w  = pr.z - pr.x + 1.0f;
    float h  = pr.w - pr.y + 1.0f;
    float cx = pr.x + 0.5f * w;
    float cy = pr.y + 0.5f * h;
    float4 rr = *(const float4*)(reg + ((size_t)j * N_CLS + cls) * 4);
    float dx = rr.x / 10.0f;
    float dy = rr.y / 10.0f;
    float dw = fminf(rr.z / 5.0f, BBOX_CLIP);
    float dh = fminf(rr.w / 5.0f, BBOX_CLIP);
    float pcx = dx * w + cx;
    float pcy = dy * h + cy;
    float pw = expf(dw) * w;
    float ph = expf(dh) * h;
    bx1 = fminf(fmaxf(pcx - 0.5f * pw, 0.0f), W1);
    by1 = fminf(fmaxf(pcy - 0.5f * ph, 0.0f), H1);
    bx2 = fminf(fmaxf(pcx + 0.5f * pw - 1.0f, 0.0f), W1);
    by2 = fminf(fmaxf(pcy + 0.5f * ph - 1.0f, 0.0f), H1);
    area = (bx2 - bx1 + 1.0f) * (by2 - by1 + 1.0f);
}

// -------- K2: one SINGLE-WAVE block per class + last-block finalize --------
__global__ __launch_bounds__(64)
void nms_kernel(const float* __restrict__ probT,
                const float* __restrict__ props,
                const float* __restrict__ reg,
                const int* __restrict__ ihp,
                const int* __restrict__ iwp,
                float* __restrict__ out,
                int* __restrict__ count,
                int* __restrict__ done,
                float* __restrict__ compact,
                int* __restrict__ svRow) {
    const int c = blockIdx.x;       // 0..79
    const int lane = threadIdx.x;   // 0..63
    const int cls = c + 1;
    const unsigned long long lm = (1ull << lane) - 1ull;

    __shared__ float sSc[N_PROP];
    __shared__ int   sIdx[N_PROP];
    __shared__ float sx1[N_PROP], sy1[N_PROP], sx2[N_PROP], sy2[N_PROP];
    __shared__ float sar[N_PROP], sSc2[N_PROP];
    __shared__ int   sJdx[N_PROP];
    __shared__ unsigned char sKeep[N_PROP];
    __shared__ float lsc[8192];

    const float W1 = (float)iwp[0] - 1.0f;
    const float H1 = (float)ihp[0] - 1.0f;

    // ---- phase 0: preload scores to registers, ballot-compact (R7-proven) ----
    float scv[16];
    #pragma unroll
    for (int it = 0; it < 16; ++it) {
        int j = it * 64 + lane;
        scv[it] = (j < N_PROP) ? probT[(size_t)c * N_PROP + j] : -1.0f;
    }
    int V = 0;
    #pragma unroll
    for (int it = 0; it < 16; ++it) {
        int j = it * 64 + lane;
        bool val = (j < N_PROP) && (scv[it] > SCORE_THRESH);
        unsigned long long mask = __ballot(val);
        if (val) { int p = V + __popcll(mask & lm); sSc[p] = scv[it]; sIdx[p] = j; }
        V += __popcll(mask);    // wave-uniform
    }
    __syncthreads();   // single wave: cheap

    // ---- phase 1: stable rank + gather + decode (R2-proven math) ----
    for (int v = lane; v < V; v += 64) {
        float s = sSc[v];
        int id = sIdx[v];
        int r = 0;
        for (int u = 0; u < V; ++u) {
            float su = sSc[u];
            r += (su > s) || (su == s && sIdx[u] < id);
        }
        float bx1, by1, bx2, by2, ar;
        decode_box(props, reg, id, cls, W1, H1, bx1, by1, bx2, by2, ar);
        sx1[r] = bx1; sy1[r] = by1; sx2[r] = bx2; sy2[r] = by2;
        sar[r] = ar; sSc2[r] = s; sJdx[r] = id; sKeep[r] = 1;
    }
    __syncthreads();

    // ---- phase 2: sequential suppression, single wave (R2-proven) ----
    for (int r = 0; r < V; ++r) {
        if (sKeep[r]) {   // lane-uniform broadcast read
            const float X1 = sx1[r], Y1 = sy1[r], X2 = sx2[r], Y2 = sy2[r], A = sar[r];
            for (int v = r + 1 + lane; v < V; v += 64) {
                if (sKeep[v]) {
                    float iw = fmaxf(fminf(X2, sx2[v]) - fmaxf(X1, sx1[v]) + 1.0f, 0.0f);
                    float ih = fmaxf(fminf(Y2, sy2[v]) - fmaxf(Y1, sy1[v]) + 1.0f, 0.0f);
                    float inter = iw * ih;
                    float iou = inter / (A + sar[v] - inter);
                    if (iou > NMS_THRESH) sKeep[v] = 0;   // NaN-safe, like ref
                }
            }
        }
        __syncthreads();   // single wave: cheap
    }

    // ---- phase 3: optimistic writes + survivor append (R4-proven) ----
    for (int v = lane; v < V; v += 64) {
        if (sKeep[v]) {
            int row = c * N_PROP + sJdx[v];
            size_t o = (size_t)row * 5;
            out[o + 0] = sx1[v]; out[o + 1] = sy1[v];
            out[o + 2] = sx2[v]; out[o + 3] = sy2[v];
            out[o + 4] = sSc2[v];
            out[LBL_OFF + row] = (float)cls;
            out[FIN_OFF + row] = 1.0f;
            int pos = atomicAdd(count, 1);
            compact[pos] = sSc2[v];
            svRow[pos] = row;
        }
    }
    __syncthreads();

    // ---- phase 4: last-block finalize (R6-proven pattern, single-wave search) ----
    __threadfence();
    int old = 0;
    if (lane == 0) old = __hip_atomic_fetch_add(done, 1, __ATOMIC_ACQ_REL, __HIP_MEMORY_SCOPE_AGENT);
    old = __shfl(old, 0);
    if (old != N_FG - 1) return;
    __threadfence();

    const int n = __hip_atomic_load(count, __ATOMIC_RELAXED, __HIP_MEMORY_SCOPE_AGENT);
    if (n <= DET_PER_IMG) return;   // th = 0 -> all survivors pass

    const bool useL = (n <= 8192);
    if (useL) {
        for (int i = lane; i < n; i += 64)
            lsc[i] = __hip_atomic_load(&compact[i], __ATOMIC_RELAXED, __HIP_MEMORY_SCOPE_AGENT);
        __syncthreads();
    }
    unsigned lo = 0x3D4CCCCCu, hi = 0x40000000u;   // scores in (0.05, 1.0]
    while (hi - lo > 1u) {
        unsigned mid = lo + ((hi - lo) >> 1);
        float mv = __uint_as_float(mid);
        int cnt = 0;
        if (useL) {
            for (int i = lane; i < n; i += 64) cnt += (lsc[i] >= mv) ? 1 : 0;
        } else {
            for (int i = lane; i < n; i += 64)
                cnt += (__hip_atomic_load(&compact[i], __ATOMIC_RELAXED, __HIP_MEMORY_SCOPE_AGENT) >= mv) ? 1 : 0;
        }
        for (int off = 32; off; off >>= 1) cnt += __shfl_xor(cnt, off);
        if (cnt >= DET_PER_IMG + 1) lo = mid; else hi = mid;   // wave-uniform
    }
    const float th = __uint_as_float(lo);

    // fixup: zero rows whose score fails the image threshold
    for (int i = lane; i < n; i += 64) {
        float sc = useL ? lsc[i]
                        : __hip_atomic_load(&compact[i], __ATOMIC_RELAXED, __HIP_MEMORY_SCOPE_AGENT);
        if (sc < th) {
            int row = __hip_atomic_load(&svRow[i], __ATOMIC_RELAXED, __HIP_MEMORY_SCOPE_AGENT);
            size_t o = (size_t)row * 5;
            out[o + 0] = 0.0f; out[o + 1] = 0.0f; out[o + 2] = 0.0f;
            out[o + 3] = 0.0f; out[o + 4] = 0.0f;
            out[LBL_OFF + row] = 0.0f;
            out[FIN_OFF + row] = 0.0f;
        }
    }
}

extern "C" void kernel_launch(void* const* d_in, const int* in_sizes, int n_in,
                              void* d_out, int out_size, void* d_ws, size_t ws_size,
                              hipStream_t stream) {
    const float* logits = (const float*)d_in[0];
    const float* reg    = (const float*)d_in[1];
    const float* props  = (const float*)d_in[2];
    const int*   ihp    = (const int*)d_in[3];
    const int*   iwp    = (const int*)d_in[4];
    float* out = (float*)d_out;

    char* ws = (char*)d_ws;
    int*   count   = (int*)(ws + 0);
    int*   done    = (int*)(ws + 4);
    float* probT   = (float*)(ws + 64);
    float* compact = (float*)(ws + 320064);
    int*   svRow   = (int*)(ws + 640064);

    softmax_zero_kernel<<<250, 256, 0, stream>>>(logits, out, count, done, probT);
    nms_kernel<<<N_FG, 64, 0, stream>>>(probT, props, reg, ihp, iwp,
                                        out, count, done, compact, svRow);
}